// Round 7
// baseline (212.501 us; speedup 1.0000x reference)
//
#include <hip/hip_runtime.h>
#include <cstdint>

#define TOPK_K 10
#define NCLS   80
#define EPS_F     1e-8f
#define IOU_EPS_F 1e-7f

typedef unsigned long long u64;
typedef float nfloat4 __attribute__((ext_vector_type(4)));  // native vec for nontemporal builtin

// sorted-desc register top-10 insert; key = (f32 bits << 32) | ~idx
// (value desc, index asc == jax.lax.top_k tie-break). val >= 0 always here.
#define INS10(val, idx)                                                     \
    {                                                                       \
        u64 key = ((u64)__float_as_uint(val) << 32) |                       \
                  (unsigned)(~(unsigned)(idx));                             \
        if (key > kk[9]) {                                                  \
            _Pragma("unroll")                                               \
            for (int q = 0; q < 10; ++q) {                                  \
                if (key > kk[q]) { u64 t_ = kk[q]; kk[q] = key; key = t_; } \
            }                                                               \
        }                                                                   \
    }

// ---------------------------------------------------------------------------
// k_init: 1 block. Detect gt_mask dtype (bool/u8 vs int32), expand to
// gmask[B*M], zero pos arrays. (No grid-wide buffers to zero anymore.)
// ---------------------------------------------------------------------------
__global__ void k_init(const unsigned char* __restrict__ gm, int n,
                       int* __restrict__ gmask,
                       unsigned int* __restrict__ pos_a,
                       unsigned int* __restrict__ pos_i)
{
    __shared__ int anynz;
    if (threadIdx.x == 0) anynz = 0;
    __syncthreads();
    for (int i = threadIdx.x; i < n; i += blockDim.x) {
        if ((i & 3) && gm[i]) anynz = 1;   // benign race
    }
    __syncthreads();
    const int is_int32 = (anynz == 0);
    const int* gi = (const int*)gm;
    for (int i = threadIdx.x; i < n; i += blockDim.x) {
        gmask[i] = is_int32 ? (gi[i] != 0) : (gm[i] != 0);
        pos_a[i] = 0u;
        pos_i[i] = 0u;
    }
}

// ---------------------------------------------------------------------------
// k_topk_geo: ONE WAVE per (b,m). Enumerate only in-box lattice cells of the
// 3 anchor levels (8400 = 80^2+40^2+20^2, strides 8/16/32); coords computed
// analytically as (j+0.5)*s (bit-exact vs the input grid). Zero-tie
// exactness: seed with the 10 lowest-index out-of-box anchors (provably
// within a=0..63). Merge = 10 rounds of shuffle butterfly; winners written to
// wl[bm][r] (-1 when out-of-box/absent). No LDS, no barriers, no atomics.
// ---------------------------------------------------------------------------
__global__ __launch_bounds__(256) void k_topk_geo(
    const float*  __restrict__ ps,    // (B,A,C)
    const float4* __restrict__ pb,    // (B,A,4)
    const int*    __restrict__ gl,    // (B,M)
    const float4* __restrict__ gb,    // (B,M,4)
    const int*    __restrict__ gmask, // (B,M)
    int*          __restrict__ wl,    // (B,M,TOPK_K)
    int B, int A, int C, int M)
{
    const int wid  = (blockIdx.x * blockDim.x + threadIdx.x) >> 6;
    const int lane = threadIdx.x & 63;
    if (wid >= B * M) return;
    const int bm = wid;
    if (!gmask[bm]) {
        if (lane < TOPK_K) wl[bm * TOPK_K + lane] = -1;
        return;
    }
    const int b = bm / M;

    const float4 g = gb[bm];
    const float areag = (g.z - g.x) * (g.w - g.y);
    const int cls = gl[bm];
    const float*  psb = ps + (size_t)b * A * C + cls;
    const float4* pbb = pb + (size_t)b * A;

    u64 kk[10];
#pragma unroll
    for (int q = 0; q < 10; ++q) kk[q] = 0ull;

    // seed: 10 lowest-index out-of-box anchors among a = 0..63 (level-0 row 0)
    {
        const float x = (lane + 0.5f) * 8.0f;
        const float y = 4.0f;
        const float d = fminf(fminf(x - g.x, y - g.y),
                              fminf(g.z - x, g.w - y));
        const u64 outb = ~__ballot(d > EPS_F);
        if (((outb >> lane) & 1ull) &&
            __popcll(outb & ((1ull << lane) - 1ull)) < TOPK_K) {
            INS10(0.0f, lane);
        }
    }

    // rect scan per level (exact d>EPS filter inside)
#define LEVEL(SS, NN, BASE)                                                   \
    {                                                                         \
        const float s_ = (float)(SS); const int n_ = (NN);                    \
        const int jlo = max(0,      (int)floorf(g.x / s_ - 0.5f));            \
        const int jhi = min(n_ - 1, (int)ceilf (g.z / s_ - 0.5f));            \
        const int ilo = max(0,      (int)floorf(g.y / s_ - 0.5f));            \
        const int ihi = min(n_ - 1, (int)ceilf (g.w / s_ - 0.5f));            \
        const int nx = jhi - jlo + 1, ny = ihi - ilo + 1;                     \
        const int tot = (nx > 0 && ny > 0) ? nx * ny : 0;                     \
        for (int c = lane; c < tot; c += 64) {                                \
            const int ci = c / nx, cj = c - ci * nx;                          \
            const int i = ilo + ci, j = jlo + cj;                             \
            const float x = (j + 0.5f) * s_, y = (i + 0.5f) * s_;             \
            const float d = fminf(fminf(x - g.x, y - g.y),                    \
                                  fminf(g.z - x, g.w - y));                   \
            if (d > EPS_F) {                                                  \
                const int a = (BASE) + i * n_ + j;                            \
                const float4 p = pbb[a];                                      \
                const float iw = fmaxf(fminf(g.z, p.z) - fmaxf(g.x, p.x), 0.f);\
                const float ih = fmaxf(fminf(g.w, p.w) - fmaxf(g.y, p.y), 0.f);\
                const float inter = iw * ih;                                  \
                const float areap = (p.z - p.x) * (p.w - p.y);                \
                const float iou = fmaxf(inter / (areag + areap - inter + IOU_EPS_F), 0.f); \
                const float sc = psb[(size_t)a * C];                          \
                const float i2 = iou * iou;                                   \
                const float al = sc * (i2 * i2 * i2);                         \
                INS10(al, a);                                                 \
            }                                                                 \
        }                                                                     \
    }
    LEVEL(8,  80, 0)
    LEVEL(16, 40, 6400)
    LEVEL(32, 20, 8000)
#undef LEVEL

    // merge: 10 rounds of 64-lane butterfly argmax + pop; lane 0 writes winner
    for (int r = 0; r < TOPK_K; ++r) {
        u64 cur = kk[0];
#pragma unroll
        for (int off = 32; off; off >>= 1) {
            const u64 o = __shfl_xor(cur, off);
            cur = (o > cur) ? o : cur;
        }
        if (kk[0] == cur) {   // unique owner pops (keys unique by index)
#pragma unroll
            for (int q = 0; q < 9; ++q) kk[q] = kk[q + 1];
            kk[9] = 0ull;
        }
        if (lane == 0) {
            int wa = -1;
            if (cur != 0ull) {
                const unsigned a = ~(unsigned)(cur & 0xFFFFFFFFull);
                float x, y;
                if (a < 6400u) {
                    const unsigned i = a / 80u, j = a - i * 80u;
                    x = (j + 0.5f) * 8.0f;  y = (i + 0.5f) * 8.0f;
                } else if (a < 8000u) {
                    const unsigned rr = a - 6400u;
                    const unsigned i = rr / 40u, j = rr - i * 40u;
                    x = (j + 0.5f) * 16.0f; y = (i + 0.5f) * 16.0f;
                } else {
                    const unsigned rr = a - 8000u;
                    const unsigned i = rr / 20u, j = rr - i * 20u;
                    x = (j + 0.5f) * 32.0f; y = (i + 0.5f) * 32.0f;
                }
                const float d = fminf(fminf(x - g.x, y - g.y),
                                      fminf(g.z - x, g.w - y));
                if (d > EPS_F) wa = (int)a;
            }
            wl[bm * TOPK_K + r] = wa;
        }
    }
}

// ---------------------------------------------------------------------------
// k_topk_fb: exact full-row sweep fallback (wave per (b,m)); used A != 8400.
// ---------------------------------------------------------------------------
__global__ __launch_bounds__(256) void k_topk_fb(
    const float*  __restrict__ ps, const float4* __restrict__ pb,
    const float2* __restrict__ apts, const int* __restrict__ gl,
    const float4* __restrict__ gb, const int* __restrict__ gmask,
    int* __restrict__ wl, int B, int A, int C, int M)
{
    const int wid  = (blockIdx.x * blockDim.x + threadIdx.x) >> 6;
    const int lane = threadIdx.x & 63;
    if (wid >= B * M) return;
    const int bm = wid;
    if (!gmask[bm]) {
        if (lane < TOPK_K) wl[bm * TOPK_K + lane] = -1;
        return;
    }
    const int b = bm / M;
    const float4 g = gb[bm];
    const float areag = (g.z - g.x) * (g.w - g.y);
    const int cls = gl[bm];
    const float*  psb = ps + (size_t)b * A * C + cls;
    const float4* pbb = pb + (size_t)b * A;

    u64 kk[10];
#pragma unroll
    for (int q = 0; q < 10; ++q) kk[q] = 0ull;

    for (int a = lane; a < A; a += 64) {
        const float2 an = apts[a];
        const float d = fminf(fminf(an.x - g.x, an.y - g.y),
                              fminf(g.z - an.x, g.w - an.y));
        float al = 0.0f;
        if (d > EPS_F) {
            const float4 p = pbb[a];
            const float iw = fmaxf(fminf(g.z, p.z) - fmaxf(g.x, p.x), 0.0f);
            const float ih = fmaxf(fminf(g.w, p.w) - fmaxf(g.y, p.y), 0.0f);
            const float inter = iw * ih;
            const float areap = (p.z - p.x) * (p.w - p.y);
            const float iou = fmaxf(inter / (areag + areap - inter + IOU_EPS_F), 0.0f);
            const float sc = psb[(size_t)a * C];
            const float i2 = iou * iou;
            al = sc * (i2 * i2 * i2);
        }
        INS10(al, a);
    }

    for (int r = 0; r < TOPK_K; ++r) {
        u64 cur = kk[0];
#pragma unroll
        for (int off = 32; off; off >>= 1) {
            const u64 o = __shfl_xor(cur, off);
            cur = (o > cur) ? o : cur;
        }
        if (kk[0] == cur) {
#pragma unroll
            for (int q = 0; q < 9; ++q) kk[q] = kk[q + 1];
            kk[9] = 0ull;
        }
        if (lane == 0) {
            int wa = -1;
            if (cur != 0ull) {
                const unsigned a = ~(unsigned)(cur & 0xFFFFFFFFull);
                const float2 an = apts[a];
                const float d = fminf(fminf(an.x - g.x, an.y - g.y),
                                      fminf(g.z - an.x, g.w - an.y));
                if (d > EPS_F) wa = (int)a;
            }
            wl[bm * TOPK_K + r] = wa;
        }
    }
}

// ---------------------------------------------------------------------------
// k_resolve: one block per (b, 256-anchor chunk). Stage winner lists + GT data
// in LDS; rebuild per-anchor GT bitmask via broadcast compares; then fg,
// multi-assignment via first-max IoU, align recompute, pos atomics, outputs.
// ---------------------------------------------------------------------------
__global__ __launch_bounds__(256) void k_resolve(
    const float*  __restrict__ ps,
    const float4* __restrict__ pb,
    const float2* __restrict__ apts,
    const int*    __restrict__ gl,
    const float4* __restrict__ gb,
    const int*    __restrict__ gmask,
    const int*    __restrict__ wl,
    int*          __restrict__ assign,
    float*        __restrict__ aval,
    unsigned int* __restrict__ pos_align,
    unsigned int* __restrict__ pos_iou,
    float*        __restrict__ out,
    int B, int A, int C, int M, int NCHK)
{
    const int b    = blockIdx.x / NCHK;
    const int chnk = blockIdx.x - b * NCHK;
    const int tid  = threadIdx.x;
    const int a    = chnk * 256 + tid;

    __shared__ int    swl[64 * TOPK_K];
    __shared__ float4 sgb[64];
    __shared__ int    sgl[64];
    __shared__ int    sgm[64];

    for (int i = tid; i < M * TOPK_K; i += 256) swl[i] = wl[b * M * TOPK_K + i];
    if (tid < M) {
        sgb[tid] = gb[b * M + tid];
        sgl[tid] = gl[b * M + tid];
        sgm[tid] = gmask[b * M + tid];
    }
    __syncthreads();
    if (a >= A) return;
    const int id = b * A + a;

    u64 bits = 0ull;
    for (int m = 0; m < M; ++m) {
        int hit = 0;
#pragma unroll
        for (int k = 0; k < TOPK_K; ++k) hit |= (swl[m * TOPK_K + k] == a);
        bits |= (u64)(hit != 0) << m;
    }

    if (bits == 0ull) {   // background: no gathers needed
        assign[id] = 0;
        aval[id]   = 0.0f;
        int lab = sgl[0];
        lab = lab < 0 ? 0 : (lab > NCLS ? NCLS : lab);
        out[id] = (float)lab;
        ((float4*)(out + (size_t)B * A))[id] = sgb[0];
        out[(size_t)B * A * (5 + NCLS) + id] = 0.0f;
        return;
    }

    const int cnt = __popcll(bits);
    int t;
    const float2 an = apts[a];
    const float4 p  = pb[id];
    const float areap = (p.z - p.x) * (p.w - p.y);

    if (cnt == 1) {
        t = __ffsll(bits) - 1;
    } else {
        float best = -1.0f; int bi = 0;
        for (int mm = 0; mm < M; ++mm) {
            const float4 gg = sgb[mm];
            const float d = fminf(fminf(an.x - gg.x, an.y - gg.y),
                                  fminf(gg.z - an.x, gg.w - an.y));
            float iou = 0.0f;
            if (d > EPS_F && sgm[mm]) {
                const float iw = fmaxf(fminf(gg.z, p.z) - fmaxf(gg.x, p.x), 0.0f);
                const float ih = fmaxf(fminf(gg.w, p.w) - fmaxf(gg.y, p.y), 0.0f);
                const float inter = iw * ih;
                const float areag = (gg.z - gg.x) * (gg.w - gg.y);
                iou = fmaxf(inter / (areag + areap - inter + IOU_EPS_F), 0.0f);
            }
            if (iou > best) { best = iou; bi = mm; }
        }
        t = bi;
    }

    float av = 0.0f;
    {
        const float4 gg = sgb[t];
        const float d = fminf(fminf(an.x - gg.x, an.y - gg.y),
                              fminf(gg.z - an.x, gg.w - an.y));
        if (d > EPS_F && sgm[t]) {
            const float iw = fmaxf(fminf(gg.z, p.z) - fmaxf(gg.x, p.x), 0.0f);
            const float ih = fmaxf(fminf(gg.w, p.w) - fmaxf(gg.y, p.y), 0.0f);
            const float inter = iw * ih;
            const float areag = (gg.z - gg.x) * (gg.w - gg.y);
            const float iou = fmaxf(inter / (areag + areap - inter + IOU_EPS_F), 0.0f);
            const float sc = ps[((size_t)b * A + a) * C + sgl[t]];
            const float i2 = iou * iou;
            av = sc * (i2 * i2 * i2);
            if (av  > 0.0f) atomicMax(&pos_align[b * M + t], __float_as_uint(av));
            if (iou > 0.0f) atomicMax(&pos_iou[b * M + t],  __float_as_uint(iou));
        }
    }

    assign[id] = t;
    aval[id]   = av;

    int lab = sgl[t];
    lab = lab < 0 ? 0 : (lab > NCLS ? NCLS : lab);
    out[id] = (float)lab;                                   // target_labels
    ((float4*)(out + (size_t)B * A))[id] = sgb[t];          // target_boxes
    out[(size_t)B * A * (5 + NCLS) + id] = 1.0f;            // fg mask
}

// ---------------------------------------------------------------------------
// k_scores2: fused norm + one-hot scores write (coalesced nontemporal stores
// via clang native vec4 — HIP_vector_type is rejected by the builtin).
// ---------------------------------------------------------------------------
__global__ void k_scores2(const int* __restrict__ assign,
                          const float* __restrict__ aval,
                          const unsigned int* __restrict__ pos_align,
                          const unsigned int* __restrict__ pos_iou,
                          const int* __restrict__ gl,
                          float* __restrict__ scores,
                          int BA, int A, int M, int C4)
{
    const int gid = blockIdx.x * blockDim.x + threadIdx.x;
    if (gid >= BA * C4) return;
    const int row = gid / C4;
    const int c4  = gid - row * C4;
    const int b   = row / A;
    const int t   = assign[row];
    const float av = aval[row];
    const float pa = __uint_as_float(pos_align[b * M + t]);
    const float pi = __uint_as_float(pos_iou[b * M + t]);
    const float nv = av * pi / (pa + EPS_F);
    int lab = gl[b * M + t];
    lab = lab < 0 ? 0 : (lab > NCLS ? NCLS : lab);
    const int cb = c4 * 4;
    nfloat4 v;
    v.x = (cb + 0 == lab) ? nv : 0.0f;
    v.y = (cb + 1 == lab) ? nv : 0.0f;
    v.z = (cb + 2 == lab) ? nv : 0.0f;
    v.w = (cb + 3 == lab) ? nv : 0.0f;
    __builtin_nontemporal_store(v, (nfloat4*)(scores + (size_t)gid * 4));
}

extern "C" void kernel_launch(void* const* d_in, const int* in_sizes, int n_in,
                              void* d_out, int out_size, void* d_ws, size_t ws_size,
                              hipStream_t stream)
{
    const float*  ps = (const float*)d_in[0];
    const float4* pb = (const float4*)d_in[1];
    const float2* ap = (const float2*)d_in[2];
    const int*    gl = (const int*)d_in[3];
    const float4* gb = (const float4*)d_in[4];
    const unsigned char* gm = (const unsigned char*)d_in[5];

    const int A = in_sizes[2] / 2;
    const int B = in_sizes[1] / (A * 4);
    const int M = in_sizes[4] / (B * 4);
    const int C = in_sizes[0] / (B * A);
    const int BA = B * A;
    const int C4 = C / 4;

    size_t off = 0;
    auto alloc = [&](size_t bytes) {
        void* p = (char*)d_ws + off;
        off += (bytes + 255) & ~(size_t)255;
        return p;
    };
    unsigned int* pos_a = (unsigned int*)alloc((size_t)B * M * 4);
    unsigned int* pos_i = (unsigned int*)alloc((size_t)B * M * 4);
    int*   gmask  = (int*)alloc((size_t)B * M * 4);
    int*   wl     = (int*)alloc((size_t)B * M * TOPK_K * 4);
    int*   assign = (int*)alloc((size_t)BA * 4);
    float* aval   = (float*)alloc((size_t)BA * 4);
    (void)off;

    float* out = (float*)d_out;

    k_init<<<1, 256, 0, stream>>>(gm, B * M, gmask, pos_a, pos_i);

    const int topk_blocks = (B * M * 64 + 255) / 256;
    if (A == 8400 && C == NCLS && M <= 64) {
        k_topk_geo<<<topk_blocks, 256, 0, stream>>>(ps, pb, gl, gb, gmask,
                                                    wl, B, A, C, M);
    } else {
        k_topk_fb<<<topk_blocks, 256, 0, stream>>>(ps, pb, ap, gl, gb, gmask,
                                                   wl, B, A, C, M);
    }

    const int NCHK = (A + 255) / 256;
    k_resolve<<<B * NCHK, 256, 0, stream>>>(
        ps, pb, ap, gl, gb, gmask, wl,
        assign, aval, pos_a, pos_i, out, B, A, C, M, NCHK);

    const int tot = BA * C4;
    k_scores2<<<(tot + 255) / 256, 256, 0, stream>>>(
        assign, aval, pos_a, pos_i, gl,
        out + (size_t)BA * 5, BA, A, M, C4);
}